// Round 10
// baseline (29951.874 us; speedup 1.0000x reference)
//
#include <hip/hip_runtime.h>
#include <math.h>

#define DN 2048
#define NT 128

#define KS   32     // k-split count for W@A parts
#define KSL  64     // k per block (KS * KSL == DN)
#define KC   16     // k per LDS stage chunk
#define CB   128    // cols per block
#define PADW 132    // padded row length in LDS

constexpr float LR    = 1e-3f;
constexpr float BETA1 = 0.9f;
constexpr float BETA2 = 0.999f;
constexpr float EPSA  = 1e-8f;

__device__ __forceinline__ float f4get(const float4& v, int k) {
    return k == 0 ? v.x : (k == 1 ? v.y : (k == 2 ? v.z : v.w));
}

// ---------------------------------------------------------------------------
// Steady-state W@A partial matmul — LDS-balanced 8x8 register tile.
// parts[kb][row][col] = sum_{k in kb-slice} W[row][k] * A[k][col]
// Block: 128 rows x 128 cols x 64 k; 256 thr (4 waves); thread = 8r x 8c
// (cols {4j..4j+3} and {64+4j..+3} to keep A-frag reads at 2-way alias).
// W staged TRANSPOSED into Ws[k][r] (conflict-free frag reads + broadcast),
// A into As[k][c]; both double-buffered per 16-k chunk, 1 barrier/chunk.
// grid (16 cb, 32 kb) = 512 blocks -> 2 blocks/CU, 2 waves/SIMD.
// Per-CU model: VALU 16.4k cyc (6.8us); LDS 4 b128 / 64 FMA-instr per thread
// -> 24.6k cyc (10.2us) worst-case -> wa ~= 10-12us (vs R8's 20.5).
__global__ __launch_bounds__(256, 2)
void wa_kernel(const float* __restrict__ W, const float* __restrict__ A,
               float* __restrict__ parts)
{
    __shared__ __align__(16) float Ws[2][KC][PADW];  // [k][r] transposed, 16.9 KB
    __shared__ __align__(16) float As[2][KC][PADW];  // [k][c],            16.9 KB
    const int c0 = blockIdx.x * CB;
    const int kb = blockIdx.y;
    const int k0 = kb * KSL;
    const int tx = threadIdx.x;
    const int i  = tx >> 4;          // 0..15: rows 8i..8i+7
    const int j  = tx & 15;          // 0..15: cols c0+{4j..4j+3, 64+4j..64+4j+3}

    // staging index decomposition (512 float4 per chunk each for W and A)
    const int wf_r = tx & 127;       // W: row (f = it*256+tx; it toggles f>>8)
    const int af_k = tx >> 5;        // A: k-row 0..7 (+8 for it=1)
    const int af_c = tx & 31;        // A: float4 within row

    float4 acc[8][2];
    #pragma unroll
    for (int m = 0; m < 8; ++m) { acc[m][0] = {0,0,0,0}; acc[m][1] = {0,0,0,0}; }

    // ---- stage chunk 0 ----
    {
        // W: 128 r x 16 k, transposed write (conflict-free: lanes span r)
        #pragma unroll
        for (int it = 0; it < 2; ++it) {
            const int f = it * 256 + tx;
            const int r = f & 127, q = f >> 7;              // q 0..3
            const float4 v = *(const float4*)&W[(size_t)r * DN + k0 + 4 * q];
            Ws[0][4 * q + 0][r] = v.x;
            Ws[0][4 * q + 1][r] = v.y;
            Ws[0][4 * q + 2][r] = v.z;
            Ws[0][4 * q + 3][r] = v.w;
        }
        // A: 16 k x 128 c, coalesced
        #pragma unroll
        for (int it = 0; it < 2; ++it) {
            const int k = it * 8 + af_k;
            *(float4*)&As[0][k][4 * af_c] =
                *(const float4*)&A[(size_t)(k0 + k) * DN + c0 + 4 * af_c];
        }
    }
    __syncthreads();

    #pragma unroll 1
    for (int ch = 0; ch < KSL / KC; ++ch) {          // 4 chunks of 16 k
        // prefetch next chunk into idle buffer (overlaps compute)
        if (ch + 1 < KSL / KC) {
            const int kc = k0 + (ch + 1) * KC;
            const int nb = (ch + 1) & 1;
            #pragma unroll
            for (int it = 0; it < 2; ++it) {
                const int f = it * 256 + tx;
                const int r = f & 127, q = f >> 7;
                const float4 v = *(const float4*)&W[(size_t)r * DN + kc + 4 * q];
                Ws[nb][4 * q + 0][r] = v.x;
                Ws[nb][4 * q + 1][r] = v.y;
                Ws[nb][4 * q + 2][r] = v.z;
                Ws[nb][4 * q + 3][r] = v.w;
            }
            #pragma unroll
            for (int it = 0; it < 2; ++it) {
                const int k = it * 8 + af_k;
                *(float4*)&As[nb][k][4 * af_c] =
                    *(const float4*)&A[(size_t)(kc + k) * DN + c0 + 4 * af_c];
            }
        }
        const int buf = ch & 1;
        #pragma unroll 8
        for (int kk = 0; kk < KC; ++kk) {
            const float4 wf0 = *(const float4*)&Ws[buf][kk][8 * i];       // rows 8i..+3
            const float4 wf1 = *(const float4*)&Ws[buf][kk][8 * i + 4];   // rows +4..+7
            const float4 af0 = *(const float4*)&As[buf][kk][4 * j];       // cols 4j..+3
            const float4 af1 = *(const float4*)&As[buf][kk][64 + 4 * j];  // cols 64+4j..
            #pragma unroll
            for (int m = 0; m < 8; ++m) {
                const float wm = (m < 4) ? f4get(wf0, m) : f4get(wf1, m - 4);
                acc[m][0].x += wm * af0.x; acc[m][0].y += wm * af0.y;
                acc[m][0].z += wm * af0.z; acc[m][0].w += wm * af0.w;
                acc[m][1].x += wm * af1.x; acc[m][1].y += wm * af1.y;
                acc[m][1].z += wm * af1.z; acc[m][1].w += wm * af1.w;
            }
        }
        __syncthreads();
    }

    float* op = parts + (size_t)kb * (NT * DN);
    #pragma unroll
    for (int m = 0; m < 8; ++m) {
        const int row = 8 * i + m;
        *(float4*)&op[(size_t)row * DN + c0 + 4 * j]      = acc[m][0];
        *(float4*)&op[(size_t)row * DN + c0 + 64 + 4 * j] = acc[m][1];
    }
}

// ---------------------------------------------------------------------------
// One-time precompute kernels (off steady-state path).
__global__ __launch_bounds__(512)
void bpart_kernel(const float* __restrict__ L, const float* __restrict__ R,
                  float* __restrict__ out_parts)
{
    __shared__ __align__(16) float Wsh[128][36];
    __shared__ __align__(16) float At[32][36];
    const int j0    = blockIdx.x * 32;
    const int kbase = blockIdx.y * 512;
    const int tx = threadIdx.x;
    const int cg = tx & 7;
    const int rg = tx >> 3;
    float4 acc0 = {0.f, 0.f, 0.f, 0.f};
    float4 acc1 = {0.f, 0.f, 0.f, 0.f};

    for (int s = 0; s < 16; ++s) {
        const int k0 = kbase + s * 32;
        {
            int idx = tx;
            #pragma unroll
            for (int rr = 0; rr < 2; ++rr) {
                const int row = idx >> 3, f = idx & 7;
                const float4 wv = *(const float4*)&L[row * DN + k0 + 4 * f];
                *(float4*)&Wsh[row][4 * f] = wv;
                idx += 512;
            }
            if (tx < 256) {
                const int c = tx >> 3, f = tx & 7;
                const float4 av = *(const float4*)&R[(size_t)(j0 + c) * DN + k0 + 4 * f];
                At[4 * f + 0][c] = av.x;
                At[4 * f + 1][c] = av.y;
                At[4 * f + 2][c] = av.z;
                At[4 * f + 3][c] = av.w;
            }
        }
        __syncthreads();
        #pragma unroll
        for (int kq = 0; kq < 8; ++kq) {
            const float4 w0 = *(const float4*)&Wsh[rg][4 * kq];
            const float4 w1 = *(const float4*)&Wsh[rg + 64][4 * kq];
            #pragma unroll
            for (int kk = 0; kk < 4; ++kk) {
                const float4 av = *(const float4*)&At[4 * kq + kk][4 * cg];
                const float wa = f4get(w0, kk);
                const float wb = f4get(w1, kk);
                acc0.x += wa * av.x; acc0.y += wa * av.y;
                acc0.z += wa * av.z; acc0.w += wa * av.w;
                acc1.x += wb * av.x; acc1.y += wb * av.y;
                acc1.z += wb * av.z; acc1.w += wb * av.w;
            }
        }
        __syncthreads();
    }
    float* op = out_parts + (size_t)blockIdx.y * (NT * DN);
    *(float4*)&op[rg * DN + j0 + 4 * cg] = acc0;
    *(float4*)&op[(rg + 64) * DN + j0 + 4 * cg] = acc1;
}

__global__ __launch_bounds__(256)
void gram_kernel(const float* __restrict__ Ht, float* __restrict__ A)
{
    __shared__ __align__(16) float Ti[64][36];
    __shared__ __align__(16) float Tj[64][36];
    const int i0 = blockIdx.x * 64, j0 = blockIdx.y * 64;
    const int tx = threadIdx.x;
    const int ti = tx & 15;
    const int tj = tx >> 4;
    float4 acc[4];
    #pragma unroll
    for (int a = 0; a < 4; ++a) acc[a] = {0.f, 0.f, 0.f, 0.f};

    for (int s = 0; s < 64; ++s) {
        const int k0 = s * 32;
        {
            int idx = tx;
            #pragma unroll
            for (int rr = 0; rr < 2; ++rr) {
                const int row = idx >> 3, f = idx & 7;
                *(float4*)&Ti[row][4 * f] = *(const float4*)&Ht[(size_t)(i0 + row) * DN + k0 + 4 * f];
                *(float4*)&Tj[row][4 * f] = *(const float4*)&Ht[(size_t)(j0 + row) * DN + k0 + 4 * f];
                idx += 256;
            }
        }
        __syncthreads();
        #pragma unroll
        for (int kq = 0; kq < 8; ++kq) {
            float4 iv[4], jv[4];
            #pragma unroll
            for (int a = 0; a < 4; ++a) iv[a] = *(const float4*)&Ti[ti + 16 * a][4 * kq];
            #pragma unroll
            for (int b = 0; b < 4; ++b) jv[b] = *(const float4*)&Tj[4 * tj + b][4 * kq];
            #pragma unroll
            for (int kk = 0; kk < 4; ++kk) {
                #pragma unroll
                for (int a = 0; a < 4; ++a) {
                    const float wa = f4get(iv[a], kk);
                    acc[a].x += wa * f4get(jv[0], kk);
                    acc[a].y += wa * f4get(jv[1], kk);
                    acc[a].z += wa * f4get(jv[2], kk);
                    acc[a].w += wa * f4get(jv[3], kk);
                }
            }
        }
        __syncthreads();
    }
    #pragma unroll
    for (int a = 0; a < 4; ++a)
        *(float4*)&A[(size_t)(i0 + ti + 16 * a) * DN + j0 + 4 * tj] = acc[a];
}

__global__ void sumB_kernel(const float* __restrict__ parts, float* __restrict__ Bm)
{
    const int idx = (blockIdx.x * 256 + threadIdx.x) * 4;
    float4 a = *(const float4*)&parts[idx];
    const float4 b = *(const float4*)&parts[(size_t)NT * DN + idx];
    const float4 c = *(const float4*)&parts[(size_t)2 * NT * DN + idx];
    const float4 d = *(const float4*)&parts[(size_t)3 * NT * DN + idx];
    a.x += b.x; a.x += c.x; a.x += d.x;
    a.y += b.y; a.y += c.y; a.y += d.y;
    a.z += b.z; a.z += c.z; a.z += d.z;
    a.w += b.w; a.w += c.w; a.w += d.w;
    *(float4*)&Bm[idx] = a;
}

__global__ void init_kernel(float* __restrict__ P, float* __restrict__ M,
                            float* __restrict__ V, float* __restrict__ W)
{
    const int idx = (blockIdx.x * 256 + threadIdx.x) * 4;
    const float4 z = {0.f, 0.f, 0.f, 0.f};
    const float u = 1.f / (float)DN;
    const float4 uu = {u, u, u, u};
    *(float4*)&P[idx] = z;
    *(float4*)&M[idx] = z;
    *(float4*)&V[idx] = z;
    *(float4*)&W[idx] = uu;
}

// ---------------------------------------------------------------------------
// Block reductions for 512 threads (8 waves).
__device__ __forceinline__ float blk_sum(float x) {
    #pragma unroll
    for (int o = 32; o > 0; o >>= 1) x += __shfl_down(x, o);
    __shared__ float r[8];
    const int tx = threadIdx.x;
    if ((tx & 63) == 0) r[tx >> 6] = x;
    __syncthreads();
    x = ((r[0] + r[1]) + (r[2] + r[3])) + ((r[4] + r[5]) + (r[6] + r[7]));
    __syncthreads();
    return x;
}

__device__ __forceinline__ float blk_max(float x) {
    #pragma unroll
    for (int o = 32; o > 0; o >>= 1) x = fmaxf(x, __shfl_down(x, o));
    __shared__ float r[8];
    const int tx = threadIdx.x;
    if ((tx & 63) == 0) r[tx >> 6] = x;
    __syncthreads();
    x = fmaxf(fmaxf(fmaxf(r[0], r[1]), fmaxf(r[2], r[3])),
              fmaxf(fmaxf(r[4], r[5]), fmaxf(r[6], r[7])));
    __syncthreads();
    return x;
}

// One row: sum KS parts -> G, softmax VJP, Adam update, next softmax.
// grid 128, block 512 (4 cols/thread).
__global__ __launch_bounds__(512)
void adam_kernel(const float* __restrict__ parts, const float* __restrict__ Bm,
                 float* __restrict__ W, float* __restrict__ P,
                 float* __restrict__ M, float* __restrict__ V,
                 const float bc1, const float bc2)
{
    const int i = blockIdx.x;
    const int tx = threadIdx.x;
    const int base = i * DN + tx * 4;

    float4 s = {0.f, 0.f, 0.f, 0.f};
    #pragma unroll
    for (int p = 0; p < KS; ++p) {
        const float4 x = *(const float4*)&parts[(size_t)p * (NT * DN) + base];
        s.x += x.x; s.y += x.y; s.z += x.z; s.w += x.w;
    }
    const float4 b = *(const float4*)&Bm[base];
    float G4[4] = { 2.f * (s.x - b.x), 2.f * (s.y - b.y),
                    2.f * (s.z - b.z), 2.f * (s.w - b.w) };

    float W4[4], P4[4], M4[4], V4[4], E4[4];
    *(float4*)&W4[0] = *(const float4*)&W[base];

    float sp = 0.f;
    #pragma unroll
    for (int e = 0; e < 4; ++e) sp += W4[e] * G4[e];
    const float srow = blk_sum(sp);

    *(float4*)&P4[0] = *(const float4*)&P[base];
    *(float4*)&M4[0] = *(const float4*)&M[base];
    *(float4*)&V4[0] = *(const float4*)&V[base];

    float mx = -1e30f;
    #pragma unroll
    for (int e = 0; e < 4; ++e) {
        const float g  = W4[e] * (G4[e] - srow);
        const float m_ = BETA1 * M4[e] + (1.f - BETA1) * g;
        const float v_ = BETA2 * V4[e] + (1.f - BETA2) * g * g;
        M4[e] = m_; V4[e] = v_;
        const float mh = m_ * bc1;
        const float vh = v_ * bc2;
        const float pn = P4[e] - LR * mh / (sqrtf(vh) + EPSA);
        P4[e] = pn;
        mx = fmaxf(mx, pn);
    }
    mx = blk_max(mx);

    float es = 0.f;
    #pragma unroll
    for (int e = 0; e < 4; ++e) { E4[e] = expf(P4[e] - mx); es += E4[e]; }
    const float sig = blk_sum(es);
    #pragma unroll
    for (int e = 0; e < 4; ++e) W4[e] = E4[e] / sig;

    *(float4*)&W[base] = *(const float4*)&W4[0];
    *(float4*)&P[base] = *(const float4*)&P4[0];
    *(float4*)&M[base] = *(const float4*)&M4[0];
    *(float4*)&V[base] = *(const float4*)&V4[0];
}

// ---------------------------------------------------------------------------
extern "C" void kernel_launch(void* const* d_in, const int* in_sizes, int n_in,
                              void* d_out, int out_size, void* d_ws, size_t ws_size,
                              hipStream_t stream)
{
    const float* H  = (const float*)d_in[0];   // [128][2048]
    const float* Ht = (const float*)d_in[1];   // [2048][2048]

    float* ws = (float*)d_ws;
    float* A     = ws;                          // 2048*2048        (16 MB)
    float* Bm    = A  + (size_t)DN * DN;        // 128*2048
    float* P     = Bm + (size_t)NT * DN;
    float* M     = P  + (size_t)NT * DN;
    float* V     = M  + (size_t)NT * DN;
    float* W     = V  + (size_t)NT * DN;
    float* parts = W  + (size_t)NT * DN;        // KS * 128*2048    (32 MB)

    // One-time precompute
    gram_kernel<<<dim3(32, 32), 256, 0, stream>>>(Ht, A);            // A = Ht Ht^T
    bpart_kernel<<<dim3(64, 4), 512, 0, stream>>>(H, Ht, parts);     // H Ht^T partials
    sumB_kernel<<<256, 256, 0, stream>>>(parts, Bm);                 // B = H Ht^T
    init_kernel<<<256, 256, 0, stream>>>(P, M, V, W);                // P=m=v=0, W=1/2048

    double b1t = 1.0, b2t = 1.0;
    for (int t = 1; t <= 1000; ++t) {
        b1t *= 0.9; b2t *= 0.999;
        wa_kernel<<<dim3(DN / CB, DN / KSL), 256, 0, stream>>>(W, A, parts);
        const float bc1 = (float)(1.0 / (1.0 - b1t));
        const float bc2 = (float)(1.0 / (1.0 - b2t));
        adam_kernel<<<NT, 512, 0, stream>>>(parts, Bm, W, P, M, V, bc1, bc2);
    }

    hipMemcpyAsync(d_out, W, (size_t)NT * DN * sizeof(float),
                   hipMemcpyDeviceToDevice, stream);
}